// Round 1
// 1843.345 us; speedup vs baseline: 1.0835x; 1.0835x over previous
//
#include <hip/hip_runtime.h>
#include <hip/hip_bf16.h>

// Problem constants
#define SEQ   256
#define HDIM  2560
#define NEXP  10
#define VOC   50257
#define VP    50304          // VOC padded to multiple of 128
#define M2    2560           // NEXP * SEQ rows for the big GEMM
#define KTILES (HDIM/32)     // 80

// Workspace layout (bytes).
#define O_H      0                        // h bf16:      256*2560*2   = 1,310,720
#define O_EH     1310720                  // EH bf16:     2560*2560*2  = 13,107,200
#define O_GATE   14417920                 // gate f32:    256*10*4     = 10,240
#define O_STATS  14428160                 // stats f32:   2560*2*4     = 20,480
#define O_LOG    14448640                 // logits bf16: 2560*50304*2 = 257,556,480
#define O_EMB    272005120                // emb bf16:    50257*2560*2 = 257,315,840
#define EMB_BYTES 257315840
#define WS_NEED  (O_EMB + (size_t)EMB_BYTES)   // 529,320,960

typedef __attribute__((ext_vector_type(8))) short bf16x8;
typedef __attribute__((ext_vector_type(4))) float f32x4;

union BPack { bf16x8 v; __hip_bfloat162 h[4]; };

__device__ __forceinline__ void ld_lds16(const void* g, void* l) {
  __builtin_amdgcn_global_load_lds(
      (const __attribute__((address_space(1))) void*)g,
      (__attribute__((address_space(3))) void*)l, 16, 0, 0);
}

// ---------------------------------------------------------------------------
// Kernel 0: one-shot f32 -> bf16 conversion of the embedding matrix.
// 50257*2560 = 128,657,920 elements = 16,082,240 groups of 8.
// ---------------------------------------------------------------------------
__global__ __launch_bounds__(256) void cvt_emb_kernel(
    const float* __restrict__ src, __hip_bfloat16* __restrict__ dst) {
  const size_t n8 = (size_t)VOC * HDIM / 8;
  size_t i = (size_t)blockIdx.x * 256 + threadIdx.x;
  const size_t stride = (size_t)gridDim.x * 256;
  const f32x4* s4 = (const f32x4*)src;
  bf16x8* d8 = (bf16x8*)dst;
  for (; i < n8; i += stride) {
    const f32x4 x0 = s4[2 * i];
    const f32x4 x1 = s4[2 * i + 1];
    BPack u;
    u.h[0] = __float22bfloat162_rn(make_float2(x0.x, x0.y));
    u.h[1] = __float22bfloat162_rn(make_float2(x0.z, x0.w));
    u.h[2] = __float22bfloat162_rn(make_float2(x1.x, x1.y));
    u.h[3] = __float22bfloat162_rn(make_float2(x1.z, x1.w));
    d8[i] = u.v;
  }
}

// ---------------------------------------------------------------------------
// Kernel 1: RMSNorm + gate softmax.  One block per sequence position.
// ---------------------------------------------------------------------------
__global__ __launch_bounds__(256) void rmsnorm_gate_kernel(
    const float* __restrict__ x, const float* __restrict__ scale,
    const float* __restrict__ gw, __hip_bfloat16* __restrict__ hbf,
    float* __restrict__ gate) {
  const int s   = blockIdx.x;
  const int tid = threadIdx.x;
  const int lane = tid & 63, wave = tid >> 6;
  const float* xr = x + (size_t)s * HDIM;

  float xi[10];
  float ss = 0.f;
#pragma unroll
  for (int j = 0; j < 10; ++j) {
    xi[j] = xr[j * 256 + tid];
    ss += xi[j] * xi[j];
  }
#pragma unroll
  for (int off = 32; off >= 1; off >>= 1) ss += __shfl_down(ss, off);
  __shared__ float red[4];
  if (lane == 0) red[wave] = ss;
  __syncthreads();
  const float tot = red[0] + red[1] + red[2] + red[3];
  const float inv = rsqrtf(tot / (float)HDIM + 1e-5f);

  float ge[NEXP];
#pragma unroll
  for (int e = 0; e < NEXP; ++e) ge[e] = 0.f;
#pragma unroll
  for (int j = 0; j < 10; ++j) {
    const int i = j * 256 + tid;
    const float hv = xi[j] * inv * scale[i];
    hbf[(size_t)s * HDIM + i] = __float2bfloat16(hv);
#pragma unroll
    for (int e = 0; e < NEXP; ++e) ge[e] += hv * gw[i * NEXP + e];
  }
#pragma unroll
  for (int e = 0; e < NEXP; ++e) {
#pragma unroll
    for (int off = 32; off >= 1; off >>= 1) ge[e] += __shfl_down(ge[e], off);
  }
  __shared__ float gred[4][NEXP];
  if (lane == 0) {
#pragma unroll
    for (int e = 0; e < NEXP; ++e) gred[wave][e] = ge[e];
  }
  __syncthreads();
  if (tid == 0) {
    float g[NEXP], mx = -1e30f, sum = 0.f;
#pragma unroll
    for (int e = 0; e < NEXP; ++e) {
      g[e] = gred[0][e] + gred[1][e] + gred[2][e] + gred[3][e];
      mx = fmaxf(mx, g[e]);
    }
#pragma unroll
    for (int e = 0; e < NEXP; ++e) { g[e] = __expf(g[e] - mx); sum += g[e]; }
#pragma unroll
    for (int e = 0; e < NEXP; ++e) gate[s * NEXP + e] = g[e] / sum;
  }
}

// ---------------------------------------------------------------------------
// Kernel 2: GEMM1  EH[e*256+s][d] = sum_h hbf[s][h] * W[e][h][d]
// A: bf16 (SEQ x HDIM).  B: f32 NN layout (k rows, n contiguous).
// 128x128 tile, BK=32, 4 waves of 4x4 16x16x32 mfma.  (unchanged)
// ---------------------------------------------------------------------------
__global__ __launch_bounds__(256) void gemm1_kernel(
    const __hip_bfloat16* __restrict__ A, const float* __restrict__ W,
    __hip_bfloat16* __restrict__ EH) {
  __shared__ short As[128 * 32];   // [row][k] bf16, 8 KB
  __shared__ float Bs[32 * 128];   // [k][chunk-swizzled n] f32, 16 KB

  const int tid = threadIdx.x;
  const int bm = blockIdx.x, bn = blockIdx.y, e = blockIdx.z;
  const int wave = tid >> 6, lane = tid & 63;
  const int wr = (wave & 1) * 64, wc = (wave >> 1) * 64;
  const int lm = lane & 15, lq = lane >> 4;
  const int row0 = bm * 128, col0 = bn * 128;
  const float* We = W + (size_t)e * HDIM * HDIM;

  f32x4 acc[4][4];
#pragma unroll
  for (int i = 0; i < 4; ++i)
#pragma unroll
    for (int j = 0; j < 4; ++j) acc[i][j] = (f32x4){0.f, 0.f, 0.f, 0.f};

  for (int kt = 0; kt < KTILES; ++kt) {
    const int k0 = kt * 32;
#pragma unroll
    for (int c = 0; c < 2; ++c) {
      const int ar = c * 64 + (tid >> 2);
      ld_lds16(A + (size_t)(row0 + ar) * HDIM + k0 + (tid & 3) * 8,
               (char*)As + c * 4096 + tid * 16);
    }
#pragma unroll
    for (int c = 0; c < 4; ++c) {
      const int L = c * 256 + tid;
      const int brow = L >> 5;
      const int cg = (L & 31) ^ (((brow >> 3) & 1) << 2);
      ld_lds16(We + (size_t)(k0 + brow) * HDIM + col0 + cg * 4,
               (char*)Bs + c * 4096 + tid * 16);
    }
    __syncthreads();

    bf16x8 a[4];
#pragma unroll
    for (int mt = 0; mt < 4; ++mt)
      a[mt] = *(const bf16x8*)&As[(wr + mt * 16 + lm) * 32 + lq * 8];
#pragma unroll
    for (int nt = 0; nt < 4; ++nt) {
      const int n = wc + nt * 16 + lm;
      const int slot = (n >> 2) ^ ((lq & 1) << 2);
      const int base = slot * 4 + (n & 3);
      BPack u;
#pragma unroll
      for (int jj = 0; jj < 4; ++jj) {
        const float f0 = Bs[(lq * 8 + 2 * jj) * 128 + base];
        const float f1 = Bs[(lq * 8 + 2 * jj + 1) * 128 + base];
        u.h[jj] = __float22bfloat162_rn(make_float2(f0, f1));
      }
#pragma unroll
      for (int mt = 0; mt < 4; ++mt)
        acc[mt][nt] = __builtin_amdgcn_mfma_f32_16x16x32_bf16(
            a[mt], u.v, acc[mt][nt], 0, 0, 0);
    }
    __syncthreads();
  }

#pragma unroll
  for (int mt = 0; mt < 4; ++mt) {
#pragma unroll
    for (int nt = 0; nt < 4; ++nt) {
#pragma unroll
      for (int i = 0; i < 4; ++i) {
        const int r = row0 + wr + mt * 16 + lq * 4 + i;   // s index
        const int d = col0 + wc + nt * 16 + lm;
        EH[((size_t)e * SEQ + r) * HDIM + d] = __float2bfloat16(acc[mt][nt][i]);
      }
    }
  }
}

// ---------------------------------------------------------------------------
// Kernel 3 (new): GEMM2 with bf16 B (B^T layout), m97 structure.
// logits[r][v] = sum_d EH[r][d] * EmbB[v][d]
// A: bf16 (M2 x HDIM).  B: bf16 (VOC x HDIM), rows clamped to VOC-1.
// Both operands staged via global_load_lds width-16, linear [row][k] LDS,
// ds_read_b128 fragments, 16 MFMA / 8 ds_read per K-step.
// Bijective XCD swizzle over nwg = 20*393 = 7860 (7860 % 8 = 4).
// ---------------------------------------------------------------------------
__global__ __launch_bounds__(256) void gemm2_bf16_kernel(
    const __hip_bfloat16* __restrict__ A, const __hip_bfloat16* __restrict__ B,
    __hip_bfloat16* __restrict__ Cl) {
  __shared__ short As[128 * 32];   // [row][k] bf16, 8 KB
  __shared__ short Bs[128 * 32];   // [vrow][k] bf16, 8 KB

  const int tid = threadIdx.x;
  // bijective XCD swizzle (m204): nwg=7860, q=982, r=4
  const int orig = blockIdx.x;
  const int q = 7860 / 8, rr = 7860 % 8;
  const int xcd = orig & 7, idx = orig >> 3;
  const int wg = (xcd < rr ? xcd * (q + 1) : rr * (q + 1) + (xcd - rr) * q) + idx;
  const int bm = wg % 20, bn = wg / 20;   // bm fast: B-panel reuse

  const int wave = tid >> 6, lane = tid & 63;
  const int wr = (wave & 1) * 64, wc = (wave >> 1) * 64;
  const int lm = lane & 15, lq = lane >> 4;
  const int row0 = bm * 128, col0 = bn * 128;

  f32x4 acc[4][4];
#pragma unroll
  for (int i = 0; i < 4; ++i)
#pragma unroll
    for (int j = 0; j < 4; ++j) acc[i][j] = (f32x4){0.f, 0.f, 0.f, 0.f};

  for (int kt = 0; kt < KTILES; ++kt) {
    const int k0 = kt * 32;
#pragma unroll
    for (int c = 0; c < 2; ++c) {
      const int ar = c * 64 + (tid >> 2);
      ld_lds16(A + (size_t)(row0 + ar) * HDIM + k0 + (tid & 3) * 8,
               (char*)As + c * 4096 + tid * 16);
    }
#pragma unroll
    for (int c = 0; c < 2; ++c) {
      const int br = c * 64 + (tid >> 2);
      const int vr = min(col0 + br, VOC - 1);
      ld_lds16(B + (size_t)vr * HDIM + k0 + (tid & 3) * 8,
               (char*)Bs + c * 4096 + tid * 16);
    }
    __syncthreads();

    bf16x8 a[4], b[4];
#pragma unroll
    for (int mt = 0; mt < 4; ++mt)
      a[mt] = *(const bf16x8*)&As[(wr + mt * 16 + lm) * 32 + lq * 8];
#pragma unroll
    for (int nt = 0; nt < 4; ++nt)
      b[nt] = *(const bf16x8*)&Bs[(wc + nt * 16 + lm) * 32 + lq * 8];
#pragma unroll
    for (int nt = 0; nt < 4; ++nt)
#pragma unroll
      for (int mt = 0; mt < 4; ++mt)
        acc[mt][nt] = __builtin_amdgcn_mfma_f32_16x16x32_bf16(
            a[mt], b[nt], acc[mt][nt], 0, 0, 0);
    __syncthreads();
  }

#pragma unroll
  for (int mt = 0; mt < 4; ++mt) {
#pragma unroll
    for (int nt = 0; nt < 4; ++nt) {
#pragma unroll
      for (int i = 0; i < 4; ++i) {
        const int r = row0 + wr + mt * 16 + lq * 4 + i;
        const int v = col0 + wc + nt * 16 + lm;
        const float val = (v < VOC) ? acc[mt][nt][i] : -INFINITY;
        Cl[(size_t)r * VP + v] = __float2bfloat16(val);
      }
    }
  }
}

// ---------------------------------------------------------------------------
// Kernel 3-fallback: old f32-B GEMM2 (used only if workspace is too small).
// ---------------------------------------------------------------------------
__global__ __launch_bounds__(256) void gemm2_kernel(
    const __hip_bfloat16* __restrict__ A, const float* __restrict__ B,
    __hip_bfloat16* __restrict__ Cl) {
  __shared__ short As[128 * 32];   // 8 KB
  __shared__ float Bs[128 * 32];   // [vrow][chunk-swizzled k] f32, 16 KB

  const int tid = threadIdx.x;
  const int bm = blockIdx.x, bn = blockIdx.y;
  const int wave = tid >> 6, lane = tid & 63;
  const int wr = (wave & 1) * 64, wc = (wave >> 1) * 64;
  const int lm = lane & 15, lq = lane >> 4;
  const int row0 = bm * 128, col0 = bn * 128;

  f32x4 acc[4][4];
#pragma unroll
  for (int i = 0; i < 4; ++i)
#pragma unroll
    for (int j = 0; j < 4; ++j) acc[i][j] = (f32x4){0.f, 0.f, 0.f, 0.f};

  for (int kt = 0; kt < KTILES; ++kt) {
    const int k0 = kt * 32;
#pragma unroll
    for (int c = 0; c < 2; ++c) {
      const int ar = c * 64 + (tid >> 2);
      ld_lds16(A + (size_t)(row0 + ar) * HDIM + k0 + (tid & 3) * 8,
               (char*)As + c * 4096 + tid * 16);
    }
#pragma unroll
    for (int c = 0; c < 4; ++c) {
      const int L = c * 256 + tid;
      const int brow = L >> 3;
      const int cg = (L & 7) ^ (brow & 7);
      const int vr = min(col0 + brow, VOC - 1);
      ld_lds16(B + (size_t)vr * HDIM + k0 + cg * 4,
               (char*)Bs + c * 4096 + tid * 16);
    }
    __syncthreads();

    bf16x8 a[4];
#pragma unroll
    for (int mt = 0; mt < 4; ++mt)
      a[mt] = *(const bf16x8*)&As[(wr + mt * 16 + lm) * 32 + lq * 8];
#pragma unroll
    for (int nt = 0; nt < 4; ++nt) {
      const int n = wc + nt * 16 + lm;
      const int r7 = n & 7;
      const f32x4 b0 = *(const f32x4*)&Bs[n * 32 + (((2 * lq) ^ r7) << 2)];
      const f32x4 b1 = *(const f32x4*)&Bs[n * 32 + (((2 * lq + 1) ^ r7) << 2)];
      BPack u;
      u.h[0] = __float22bfloat162_rn(make_float2(b0.x, b0.y));
      u.h[1] = __float22bfloat162_rn(make_float2(b0.z, b0.w));
      u.h[2] = __float22bfloat162_rn(make_float2(b1.x, b1.y));
      u.h[3] = __float22bfloat162_rn(make_float2(b1.z, b1.w));
#pragma unroll
      for (int mt = 0; mt < 4; ++mt)
        acc[mt][nt] = __builtin_amdgcn_mfma_f32_16x16x32_bf16(
            a[mt], u.v, acc[mt][nt], 0, 0, 0);
    }
    __syncthreads();
  }

#pragma unroll
  for (int mt = 0; mt < 4; ++mt) {
#pragma unroll
    for (int nt = 0; nt < 4; ++nt) {
#pragma unroll
      for (int i = 0; i < 4; ++i) {
        const int r = row0 + wr + mt * 16 + lq * 4 + i;
        const int v = col0 + wc + nt * 16 + lm;
        const float val = (v < VOC) ? acc[mt][nt][i] : -INFINITY;
        Cl[(size_t)r * VP + v] = __float2bfloat16(val);
      }
    }
  }
}

// ---------------------------------------------------------------------------
// Kernel 4: per-row softmax stats.  stats[2r]=max, stats[2r+1]=gate/sumexp.
// ---------------------------------------------------------------------------
__global__ __launch_bounds__(256) void softmax_stats_kernel(
    const __hip_bfloat16* __restrict__ Cl, const float* __restrict__ gate,
    float* __restrict__ stats) {
  const int r = blockIdx.x;
  const int tid = threadIdx.x;
  const bf16x8* row = (const bf16x8*)(Cl + (size_t)r * VP);

  float m = -1e30f, l = 0.f;
  for (int c = tid; c < VP / 8; c += 256) {
    const bf16x8 ch = row[c];
    float x[8];
#pragma unroll
    for (int j = 0; j < 8; ++j)
      x[j] = __bfloat162float(((const __hip_bfloat16*)&ch)[j]);
    float lm = x[0];
#pragma unroll
    for (int j = 1; j < 8; ++j) lm = fmaxf(lm, x[j]);
    if (lm > m) { l *= __expf(m - lm); m = lm; }
#pragma unroll
    for (int j = 0; j < 8; ++j) l += __expf(x[j] - m);
  }
#pragma unroll
  for (int off = 32; off >= 1; off >>= 1) {
    const float m2 = __shfl_down(m, off);
    const float l2 = __shfl_down(l, off);
    const float nm = fmaxf(m, m2);
    l = l * __expf(m - nm) + l2 * __expf(m2 - nm);
    m = nm;
  }
  __shared__ float sm[4], sl[4];
  if ((tid & 63) == 0) { sm[tid >> 6] = m; sl[tid >> 6] = l; }
  __syncthreads();
  if (tid == 0) {
    float M = sm[0], L = sl[0];
#pragma unroll
    for (int w = 1; w < 4; ++w) {
      const float nm = fmaxf(M, sm[w]);
      L = L * __expf(M - nm) + sl[w] * __expf(sm[w] - nm);
      M = nm;
    }
    const int e = r >> 8, s = r & 255;
    stats[2 * r] = M;
    stats[2 * r + 1] = gate[s * NEXP + e] / L;   // fold gate/Z into one coef
  }
}

// ---------------------------------------------------------------------------
// Kernel 5: mixture + log.
// ---------------------------------------------------------------------------
__global__ __launch_bounds__(256) void mix_kernel(
    const __hip_bfloat16* __restrict__ Cl, const float* __restrict__ stats,
    float* __restrict__ out) {
  const int s = blockIdx.y;
  const int v = blockIdx.x * 256 + threadIdx.x;
  if (v >= VOC) return;
  float acc = 1e-10f;
#pragma unroll
  for (int e = 0; e < NEXP; ++e) {
    const int r = e * SEQ + s;
    const float le = __bfloat162float(Cl[(size_t)r * VP + v]);
    acc = fmaf(stats[2 * r + 1], __expf(le - stats[2 * r]), acc);
  }
  out[(size_t)s * VOC + v] = __logf(acc);
}

// ---------------------------------------------------------------------------
extern "C" void kernel_launch(void* const* d_in, const int* in_sizes, int n_in,
                              void* d_out, int out_size, void* d_ws, size_t ws_size,
                              hipStream_t stream) {
  const float* x      = (const float*)d_in[0];   // (1,256,2560)
  const float* emb    = (const float*)d_in[1];   // (50257,2560)
  const float* nscale = (const float*)d_in[2];   // (2560,)
  const float* ew     = (const float*)d_in[3];   // (10,2560,2560)
  const float* gw     = (const float*)d_in[4];   // (2560,10)
  float* out = (float*)d_out;

  char* ws = (char*)d_ws;
  __hip_bfloat16* hbf    = (__hip_bfloat16*)(ws + O_H);
  __hip_bfloat16* eh     = (__hip_bfloat16*)(ws + O_EH);
  float*          gate   = (float*)(ws + O_GATE);
  float*          stats  = (float*)(ws + O_STATS);
  __hip_bfloat16* logits = (__hip_bfloat16*)(ws + O_LOG);

  const bool have_emb_ws = (ws_size >= WS_NEED);

  if (have_emb_ws) {
    __hip_bfloat16* embb = (__hip_bfloat16*)(ws + O_EMB);
    cvt_emb_kernel<<<2048, 256, 0, stream>>>(emb, embb);
    rmsnorm_gate_kernel<<<SEQ, 256, 0, stream>>>(x, nscale, gw, hbf, gate);
    gemm1_kernel<<<dim3(2, HDIM / 128, NEXP), 256, 0, stream>>>(hbf, ew, eh);
    gemm2_bf16_kernel<<<(M2 / 128) * (VP / 128), 256, 0, stream>>>(eh, embb, logits);
  } else {
    rmsnorm_gate_kernel<<<SEQ, 256, 0, stream>>>(x, nscale, gw, hbf, gate);
    gemm1_kernel<<<dim3(2, HDIM / 128, NEXP), 256, 0, stream>>>(hbf, ew, eh);
    gemm2_kernel<<<dim3(M2 / 128, VP / 128), 256, 0, stream>>>(eh, emb, logits);
  }
  softmax_stats_kernel<<<M2, 256, 0, stream>>>(logits, gate, stats);
  mix_kernel<<<dim3((VOC + 255) / 256, SEQ), 256, 0, stream>>>(logits, stats, out);
}

// Round 2
// 1578.178 us; speedup vs baseline: 1.2656x; 1.1680x over previous
//
#include <hip/hip_runtime.h>
#include <hip/hip_bf16.h>

// Problem constants
#define SEQ   256
#define HDIM  2560
#define NEXP  10
#define VOC   50257
#define VP    50304          // VOC padded to multiple of 128
#define M2    2560           // NEXP * SEQ rows for the big GEMM
#define KTILES (HDIM/32)     // 80 (for the 128-tile kernels)
#define NT2   (HDIM/64)      // 40 K-tiles for the 8-phase gemm2

// Workspace layout (bytes).
#define O_H      0                        // h bf16:      256*2560*2   = 1,310,720
#define O_EH     1310720                  // EH bf16:     2560*2560*2  = 13,107,200
#define O_GATE   14417920                 // gate f32:    256*10*4     = 10,240
#define O_STATS  14428160                 // stats f32:   2560*2*4     = 20,480
#define O_LOG    14448640                 // logits bf16: 2560*50304*2 = 257,556,480
#define O_EMB    272005120                // emb bf16:    50257*2560*2 = 257,315,840
#define EMB_BYTES 257315840
#define WS_NEED  (O_EMB + (size_t)EMB_BYTES)   // 529,320,960

typedef __attribute__((ext_vector_type(8))) short bf16x8;
typedef __attribute__((ext_vector_type(4))) float f32x4;

union BPack { bf16x8 v; __hip_bfloat162 h[4]; };

__device__ __forceinline__ void ld_lds16(const void* g, void* l) {
  __builtin_amdgcn_global_load_lds(
      (const __attribute__((address_space(1))) void*)g,
      (__attribute__((address_space(3))) void*)l, 16, 0, 0);
}

// ---------------------------------------------------------------------------
// Kernel 0: one-shot f32 -> bf16 conversion of the embedding matrix.
// ---------------------------------------------------------------------------
__global__ __launch_bounds__(256) void cvt_emb_kernel(
    const float* __restrict__ src, __hip_bfloat16* __restrict__ dst) {
  const size_t n8 = (size_t)VOC * HDIM / 8;
  size_t i = (size_t)blockIdx.x * 256 + threadIdx.x;
  const size_t stride = (size_t)gridDim.x * 256;
  const f32x4* s4 = (const f32x4*)src;
  bf16x8* d8 = (bf16x8*)dst;
  for (; i < n8; i += stride) {
    const f32x4 x0 = s4[2 * i];
    const f32x4 x1 = s4[2 * i + 1];
    BPack u;
    u.h[0] = __float22bfloat162_rn(make_float2(x0.x, x0.y));
    u.h[1] = __float22bfloat162_rn(make_float2(x0.z, x0.w));
    u.h[2] = __float22bfloat162_rn(make_float2(x1.x, x1.y));
    u.h[3] = __float22bfloat162_rn(make_float2(x1.z, x1.w));
    d8[i] = u.v;
  }
}

// ---------------------------------------------------------------------------
// Kernel 1: RMSNorm + gate softmax.  One block per sequence position.
// ---------------------------------------------------------------------------
__global__ __launch_bounds__(256) void rmsnorm_gate_kernel(
    const float* __restrict__ x, const float* __restrict__ scale,
    const float* __restrict__ gw, __hip_bfloat16* __restrict__ hbf,
    float* __restrict__ gate) {
  const int s   = blockIdx.x;
  const int tid = threadIdx.x;
  const int lane = tid & 63, wave = tid >> 6;
  const float* xr = x + (size_t)s * HDIM;

  float xi[10];
  float ss = 0.f;
#pragma unroll
  for (int j = 0; j < 10; ++j) {
    xi[j] = xr[j * 256 + tid];
    ss += xi[j] * xi[j];
  }
#pragma unroll
  for (int off = 32; off >= 1; off >>= 1) ss += __shfl_down(ss, off);
  __shared__ float red[4];
  if (lane == 0) red[wave] = ss;
  __syncthreads();
  const float tot = red[0] + red[1] + red[2] + red[3];
  const float inv = rsqrtf(tot / (float)HDIM + 1e-5f);

  float ge[NEXP];
#pragma unroll
  for (int e = 0; e < NEXP; ++e) ge[e] = 0.f;
#pragma unroll
  for (int j = 0; j < 10; ++j) {
    const int i = j * 256 + tid;
    const float hv = xi[j] * inv * scale[i];
    hbf[(size_t)s * HDIM + i] = __float2bfloat16(hv);
#pragma unroll
    for (int e = 0; e < NEXP; ++e) ge[e] += hv * gw[i * NEXP + e];
  }
#pragma unroll
  for (int e = 0; e < NEXP; ++e) {
#pragma unroll
    for (int off = 32; off >= 1; off >>= 1) ge[e] += __shfl_down(ge[e], off);
  }
  __shared__ float gred[4][NEXP];
  if (lane == 0) {
#pragma unroll
    for (int e = 0; e < NEXP; ++e) gred[wave][e] = ge[e];
  }
  __syncthreads();
  if (tid == 0) {
    float g[NEXP], mx = -1e30f, sum = 0.f;
#pragma unroll
    for (int e = 0; e < NEXP; ++e) {
      g[e] = gred[0][e] + gred[1][e] + gred[2][e] + gred[3][e];
      mx = fmaxf(mx, g[e]);
    }
#pragma unroll
    for (int e = 0; e < NEXP; ++e) { g[e] = __expf(g[e] - mx); sum += g[e]; }
#pragma unroll
    for (int e = 0; e < NEXP; ++e) gate[s * NEXP + e] = g[e] / sum;
  }
}

// ---------------------------------------------------------------------------
// Kernel 2: GEMM1  EH[e*256+s][d] = sum_h hbf[s][h] * W[e][h][d]  (unchanged)
// ---------------------------------------------------------------------------
__global__ __launch_bounds__(256) void gemm1_kernel(
    const __hip_bfloat16* __restrict__ A, const float* __restrict__ W,
    __hip_bfloat16* __restrict__ EH) {
  __shared__ short As[128 * 32];   // [row][k] bf16, 8 KB
  __shared__ float Bs[32 * 128];   // [k][chunk-swizzled n] f32, 16 KB

  const int tid = threadIdx.x;
  const int bm = blockIdx.x, bn = blockIdx.y, e = blockIdx.z;
  const int wave = tid >> 6, lane = tid & 63;
  const int wr = (wave & 1) * 64, wc = (wave >> 1) * 64;
  const int lm = lane & 15, lq = lane >> 4;
  const int row0 = bm * 128, col0 = bn * 128;
  const float* We = W + (size_t)e * HDIM * HDIM;

  f32x4 acc[4][4];
#pragma unroll
  for (int i = 0; i < 4; ++i)
#pragma unroll
    for (int j = 0; j < 4; ++j) acc[i][j] = (f32x4){0.f, 0.f, 0.f, 0.f};

  for (int kt = 0; kt < KTILES; ++kt) {
    const int k0 = kt * 32;
#pragma unroll
    for (int c = 0; c < 2; ++c) {
      const int ar = c * 64 + (tid >> 2);
      ld_lds16(A + (size_t)(row0 + ar) * HDIM + k0 + (tid & 3) * 8,
               (char*)As + c * 4096 + tid * 16);
    }
#pragma unroll
    for (int c = 0; c < 4; ++c) {
      const int L = c * 256 + tid;
      const int brow = L >> 5;
      const int cg = (L & 31) ^ (((brow >> 3) & 1) << 2);
      ld_lds16(We + (size_t)(k0 + brow) * HDIM + col0 + cg * 4,
               (char*)Bs + c * 4096 + tid * 16);
    }
    __syncthreads();

    bf16x8 a[4];
#pragma unroll
    for (int mt = 0; mt < 4; ++mt)
      a[mt] = *(const bf16x8*)&As[(wr + mt * 16 + lm) * 32 + lq * 8];
#pragma unroll
    for (int nt = 0; nt < 4; ++nt) {
      const int n = wc + nt * 16 + lm;
      const int slot = (n >> 2) ^ ((lq & 1) << 2);
      const int base = slot * 4 + (n & 3);
      BPack u;
#pragma unroll
      for (int jj = 0; jj < 4; ++jj) {
        const float f0 = Bs[(lq * 8 + 2 * jj) * 128 + base];
        const float f1 = Bs[(lq * 8 + 2 * jj + 1) * 128 + base];
        u.h[jj] = __float22bfloat162_rn(make_float2(f0, f1));
      }
#pragma unroll
      for (int mt = 0; mt < 4; ++mt)
        acc[mt][nt] = __builtin_amdgcn_mfma_f32_16x16x32_bf16(
            a[mt], u.v, acc[mt][nt], 0, 0, 0);
    }
    __syncthreads();
  }

#pragma unroll
  for (int mt = 0; mt < 4; ++mt) {
#pragma unroll
    for (int nt = 0; nt < 4; ++nt) {
#pragma unroll
      for (int i = 0; i < 4; ++i) {
        const int r = row0 + wr + mt * 16 + lq * 4 + i;   // s index
        const int d = col0 + wc + nt * 16 + lm;
        EH[((size_t)e * SEQ + r) * HDIM + d] = __float2bfloat16(acc[mt][nt][i]);
      }
    }
  }
}

// ---------------------------------------------------------------------------
// Kernel 3 (new): GEMM2, 256x256 tile, BK=64, 8-phase counted-vmcnt schedule.
// logits[r][v] = sum_d EH[r][d] * EmbB[v][d]   (both bf16, B^T layout)
//
// LDS (128 KiB): 2 K-tile buffers; each buffer = {A-k0, A-k1, B-k0, B-k1},
// each half 16 KiB covering all 256 rows x 32 k, stored as
//   line = row & 127, logical slot s = (row>>7)*4 + k-chunk (16B chunks),
//   physical slot = s ^ (line & 7)   (XOR swizzle, both-sides: staging
//   pre-swizzles the GLOBAL source so the LDS dest stays linear).
// Per K-tile: 4 phases (kk0/nt01, kk0/nt23, kk1/nt01, kk1/nt23), each phase
// {ds_read frags, issue ONE half-tile prefetch (2 x global_load_lds),
//  setprio(1) 16 MFMA setprio(0)}.  Sync: vmcnt(8)+s_barrier at tile entry
// and mid-tile only -> every prefetch has a 6-phase lead, never drains to 0.
// Stage schedule in tile t: ph1: A-k1(t+1)  ph2: B-k1(t+1)
//                           ph3: A-k0(t+2)  ph4: B-k0(t+2)
// (targets are regions whose last readers are behind the preceding barrier).
// ---------------------------------------------------------------------------
__device__ __forceinline__ void stage_half(
    const __hip_bfloat16* __restrict__ G, int rowbase, int kbase,
    char* lds_half, int tid, bool clampB) {
#pragma unroll
  for (int c = 0; c < 2; ++c) {
    const int line = c * 64 + (tid >> 3);
    const int slog = (tid & 7) ^ (line & 7);
    int row = rowbase + line + ((slog & 4) << 5);   // +128 if slog>=4
    if (clampB) row = min(row, VOC - 1);
    ld_lds16(G + (size_t)row * HDIM + kbase + (slog & 3) * 8,
             lds_half + c * 8192 + tid * 16);
  }
}

__device__ __forceinline__ bf16x8 frag_rd(const char* half, int row, int lq) {
  const int line = row & 127;
  const int slot = (((row >> 7) << 2) | lq) ^ (line & 7);
  return *(const bf16x8*)(half + line * 128 + slot * 16);
}

__device__ __forceinline__ void wait_barrier8() {
  asm volatile("s_waitcnt vmcnt(8)" ::: "memory");
  __builtin_amdgcn_s_barrier();
  asm volatile("" ::: "memory");
}

__global__ __launch_bounds__(512) void gemm2_8ph_kernel(
    const __hip_bfloat16* __restrict__ A, const __hip_bfloat16* __restrict__ B,
    __hip_bfloat16* __restrict__ Cl) {
  __shared__ char smem[131072];
  const int tid = threadIdx.x;
  const int wave = tid >> 6, lane = tid & 63;
  const int lm = lane & 15, lq = (lane >> 4) & 3;
  const int wm = wave >> 2, wn = wave & 3;   // 2 x 4 wave grid

  // bijective XCD swizzle (m204): nwg = 10*197 = 1970 = 8*246 + 2
  const int orig = blockIdx.x;
  const int xcd = orig & 7, idx = orig >> 3;
  const int wg = (xcd < 2 ? xcd * 247 : 494 + (xcd - 2) * 246) + idx;
  const int bm = wg % 10, bn = wg / 10;     // bm fast: B-panel reuse in L2
  const int row0 = bm * 256, col0 = bn * 256;

  f32x4 acc[8][4];
#pragma unroll
  for (int i = 0; i < 8; ++i)
#pragma unroll
    for (int j = 0; j < 4; ++j) acc[i][j] = (f32x4){0.f, 0.f, 0.f, 0.f};

  // Prologue: 6 half-tiles, oldest-first (12 global_load_lds).
  stage_half(A, row0, 0,  smem + 0,     tid, false);   // A-k0 (t0) -> buf0
  stage_half(B, col0, 0,  smem + 32768, tid, true);    // B-k0 (t0)
  stage_half(A, row0, 32, smem + 16384, tid, false);   // A-k1 (t0)
  stage_half(B, col0, 32, smem + 49152, tid, true);    // B-k1 (t0)
  stage_half(A, row0, 64, smem + 65536, tid, false);   // A-k0 (t1) -> buf1
  stage_half(B, col0, 64, smem + 98304, tid, true);    // B-k0 (t1)

  const int arow = wm * 128 + lm;   // + mt*16
  const int brow = wn * 64 + lm;    // + nt*16

  for (int t = 0; t < NT2; ++t) {
    char* rb = smem + (t & 1) * 65536;          // buffer holding tile t
    char* wb = smem + ((t + 1) & 1) * 65536;    // prefetch buffer (tile t+1)
    const char* A0 = rb;
    const char* A1 = rb + 16384;
    const char* B0 = rb + 32768;
    const char* B1 = rb + 49152;

    wait_barrier8();
    // ---- phase 1: kk0, nt 0-1 ----
    bf16x8 a[8], b0, b1;
#pragma unroll
    for (int mt = 0; mt < 8; ++mt) a[mt] = frag_rd(A0, arow + mt * 16, lq);
    b0 = frag_rd(B0, brow + 0, lq);
    b1 = frag_rd(B0, brow + 16, lq);
    if (t + 1 < NT2) stage_half(A, row0, (t + 1) * 64 + 32, wb + 16384, tid, false);
    __builtin_amdgcn_s_setprio(1);
#pragma unroll
    for (int mt = 0; mt < 8; ++mt) {
      acc[mt][0] = __builtin_amdgcn_mfma_f32_16x16x32_bf16(a[mt], b0, acc[mt][0], 0, 0, 0);
      acc[mt][1] = __builtin_amdgcn_mfma_f32_16x16x32_bf16(a[mt], b1, acc[mt][1], 0, 0, 0);
    }
    __builtin_amdgcn_s_setprio(0);
    // ---- phase 2: kk0, nt 2-3 ----
    b0 = frag_rd(B0, brow + 32, lq);
    b1 = frag_rd(B0, brow + 48, lq);
    if (t + 1 < NT2) stage_half(B, col0, (t + 1) * 64 + 32, wb + 49152, tid, true);
    __builtin_amdgcn_s_setprio(1);
#pragma unroll
    for (int mt = 0; mt < 8; ++mt) {
      acc[mt][2] = __builtin_amdgcn_mfma_f32_16x16x32_bf16(a[mt], b0, acc[mt][2], 0, 0, 0);
      acc[mt][3] = __builtin_amdgcn_mfma_f32_16x16x32_bf16(a[mt], b1, acc[mt][3], 0, 0, 0);
    }
    __builtin_amdgcn_s_setprio(0);

    wait_barrier8();
    // ---- phase 3: kk1, nt 0-1 ----
#pragma unroll
    for (int mt = 0; mt < 8; ++mt) a[mt] = frag_rd(A1, arow + mt * 16, lq);
    b0 = frag_rd(B1, brow + 0, lq);
    b1 = frag_rd(B1, brow + 16, lq);
    if (t + 2 < NT2) stage_half(A, row0, (t + 2) * 64, rb, tid, false);
    __builtin_amdgcn_s_setprio(1);
#pragma unroll
    for (int mt = 0; mt < 8; ++mt) {
      acc[mt][0] = __builtin_amdgcn_mfma_f32_16x16x32_bf16(a[mt], b0, acc[mt][0], 0, 0, 0);
      acc[mt][1] = __builtin_amdgcn_mfma_f32_16x16x32_bf16(a[mt], b1, acc[mt][1], 0, 0, 0);
    }
    __builtin_amdgcn_s_setprio(0);
    // ---- phase 4: kk1, nt 2-3 ----
    b0 = frag_rd(B1, brow + 32, lq);
    b1 = frag_rd(B1, brow + 48, lq);
    if (t + 2 < NT2) stage_half(B, col0, (t + 2) * 64, rb + 32768, tid, true);
    __builtin_amdgcn_s_setprio(1);
#pragma unroll
    for (int mt = 0; mt < 8; ++mt) {
      acc[mt][2] = __builtin_amdgcn_mfma_f32_16x16x32_bf16(a[mt], b0, acc[mt][2], 0, 0, 0);
      acc[mt][3] = __builtin_amdgcn_mfma_f32_16x16x32_bf16(a[mt], b1, acc[mt][3], 0, 0, 0);
    }
    __builtin_amdgcn_s_setprio(0);
  }

  // Epilogue: C mapping col=lane&15, row=(lane>>4)*4+i
#pragma unroll
  for (int mt = 0; mt < 8; ++mt) {
#pragma unroll
    for (int nt = 0; nt < 4; ++nt) {
#pragma unroll
      for (int i = 0; i < 4; ++i) {
        const int r = row0 + wm * 128 + mt * 16 + lq * 4 + i;
        const int v = col0 + wn * 64 + nt * 16 + lm;
        if (v < VP) {
          const float val = (v < VOC) ? acc[mt][nt][i] : -INFINITY;
          Cl[(size_t)r * VP + v] = __float2bfloat16(val);
        }
      }
    }
  }
}

// ---------------------------------------------------------------------------
// Kernel 3-fallback: old f32-B GEMM2 (used only if workspace is too small).
// ---------------------------------------------------------------------------
__global__ __launch_bounds__(256) void gemm2_kernel(
    const __hip_bfloat16* __restrict__ A, const float* __restrict__ B,
    __hip_bfloat16* __restrict__ Cl) {
  __shared__ short As[128 * 32];   // 8 KB
  __shared__ float Bs[128 * 32];   // [vrow][chunk-swizzled k] f32, 16 KB

  const int tid = threadIdx.x;
  const int bm = blockIdx.x, bn = blockIdx.y;
  const int wave = tid >> 6, lane = tid & 63;
  const int wr = (wave & 1) * 64, wc = (wave >> 1) * 64;
  const int lm = lane & 15, lq = lane >> 4;
  const int row0 = bm * 128, col0 = bn * 128;

  f32x4 acc[4][4];
#pragma unroll
  for (int i = 0; i < 4; ++i)
#pragma unroll
    for (int j = 0; j < 4; ++j) acc[i][j] = (f32x4){0.f, 0.f, 0.f, 0.f};

  for (int kt = 0; kt < KTILES; ++kt) {
    const int k0 = kt * 32;
#pragma unroll
    for (int c = 0; c < 2; ++c) {
      const int ar = c * 64 + (tid >> 2);
      ld_lds16(A + (size_t)(row0 + ar) * HDIM + k0 + (tid & 3) * 8,
               (char*)As + c * 4096 + tid * 16);
    }
#pragma unroll
    for (int c = 0; c < 4; ++c) {
      const int L = c * 256 + tid;
      const int brow = L >> 3;
      const int cg = (L & 7) ^ (brow & 7);
      const int vr = min(col0 + brow, VOC - 1);
      ld_lds16(B + (size_t)vr * HDIM + k0 + cg * 4,
               (char*)Bs + c * 4096 + tid * 16);
    }
    __syncthreads();

    bf16x8 a[4];
#pragma unroll
    for (int mt = 0; mt < 4; ++mt)
      a[mt] = *(const bf16x8*)&As[(wr + mt * 16 + lm) * 32 + lq * 8];
#pragma unroll
    for (int nt = 0; nt < 4; ++nt) {
      const int n = wc + nt * 16 + lm;
      const int r7 = n & 7;
      const f32x4 b0 = *(const f32x4*)&Bs[n * 32 + (((2 * lq) ^ r7) << 2)];
      const f32x4 b1 = *(const f32x4*)&Bs[n * 32 + (((2 * lq + 1) ^ r7) << 2)];
      BPack u;
      u.h[0] = __float22bfloat162_rn(make_float2(b0.x, b0.y));
      u.h[1] = __float22bfloat162_rn(make_float2(b0.z, b0.w));
      u.h[2] = __float22bfloat162_rn(make_float2(b1.x, b1.y));
      u.h[3] = __float22bfloat162_rn(make_float2(b1.z, b1.w));
#pragma unroll
      for (int mt = 0; mt < 4; ++mt)
        acc[mt][nt] = __builtin_amdgcn_mfma_f32_16x16x32_bf16(
            a[mt], u.v, acc[mt][nt], 0, 0, 0);
    }
    __syncthreads();
  }

#pragma unroll
  for (int mt = 0; mt < 4; ++mt) {
#pragma unroll
    for (int nt = 0; nt < 4; ++nt) {
#pragma unroll
      for (int i = 0; i < 4; ++i) {
        const int r = row0 + wr + mt * 16 + lq * 4 + i;
        const int v = col0 + wc + nt * 16 + lm;
        const float val = (v < VOC) ? acc[mt][nt][i] : -INFINITY;
        Cl[(size_t)r * VP + v] = __float2bfloat16(val);
      }
    }
  }
}

// ---------------------------------------------------------------------------
// Kernel 4: per-row softmax stats.  stats[2r]=max, stats[2r+1]=gate/sumexp.
// ---------------------------------------------------------------------------
__global__ __launch_bounds__(256) void softmax_stats_kernel(
    const __hip_bfloat16* __restrict__ Cl, const float* __restrict__ gate,
    float* __restrict__ stats) {
  const int r = blockIdx.x;
  const int tid = threadIdx.x;
  const bf16x8* row = (const bf16x8*)(Cl + (size_t)r * VP);

  float m = -1e30f, l = 0.f;
  for (int c = tid; c < VP / 8; c += 256) {
    const bf16x8 ch = row[c];
    float x[8];
#pragma unroll
    for (int j = 0; j < 8; ++j)
      x[j] = __bfloat162float(((const __hip_bfloat16*)&ch)[j]);
    float lm = x[0];
#pragma unroll
    for (int j = 1; j < 8; ++j) lm = fmaxf(lm, x[j]);
    if (lm > m) { l *= __expf(m - lm); m = lm; }
#pragma unroll
    for (int j = 0; j < 8; ++j) l += __expf(x[j] - m);
  }
#pragma unroll
  for (int off = 32; off >= 1; off >>= 1) {
    const float m2 = __shfl_down(m, off);
    const float l2 = __shfl_down(l, off);
    const float nm = fmaxf(m, m2);
    l = l * __expf(m - nm) + l2 * __expf(m2 - nm);
    m = nm;
  }
  __shared__ float sm[4], sl[4];
  if ((tid & 63) == 0) { sm[tid >> 6] = m; sl[tid >> 6] = l; }
  __syncthreads();
  if (tid == 0) {
    float M = sm[0], L = sl[0];
#pragma unroll
    for (int w = 1; w < 4; ++w) {
      const float nm = fmaxf(M, sm[w]);
      L = L * __expf(M - nm) + sl[w] * __expf(sm[w] - nm);
      M = nm;
    }
    const int e = r >> 8, s = r & 255;
    stats[2 * r] = M;
    stats[2 * r + 1] = gate[s * NEXP + e] / L;   // fold gate/Z into one coef
  }
}

// ---------------------------------------------------------------------------
// Kernel 5: mixture + log.
// ---------------------------------------------------------------------------
__global__ __launch_bounds__(256) void mix_kernel(
    const __hip_bfloat16* __restrict__ Cl, const float* __restrict__ stats,
    float* __restrict__ out) {
  const int s = blockIdx.y;
  const int v = blockIdx.x * 256 + threadIdx.x;
  if (v >= VOC) return;
  float acc = 1e-10f;
#pragma unroll
  for (int e = 0; e < NEXP; ++e) {
    const int r = e * SEQ + s;
    const float le = __bfloat162float(Cl[(size_t)r * VP + v]);
    acc = fmaf(stats[2 * r + 1], __expf(le - stats[2 * r]), acc);
  }
  out[(size_t)s * VOC + v] = __logf(acc);
}

// ---------------------------------------------------------------------------
extern "C" void kernel_launch(void* const* d_in, const int* in_sizes, int n_in,
                              void* d_out, int out_size, void* d_ws, size_t ws_size,
                              hipStream_t stream) {
  const float* x      = (const float*)d_in[0];   // (1,256,2560)
  const float* emb    = (const float*)d_in[1];   // (50257,2560)
  const float* nscale = (const float*)d_in[2];   // (2560,)
  const float* ew     = (const float*)d_in[3];   // (10,2560,2560)
  const float* gw     = (const float*)d_in[4];   // (2560,10)
  float* out = (float*)d_out;

  char* ws = (char*)d_ws;
  __hip_bfloat16* hbf    = (__hip_bfloat16*)(ws + O_H);
  __hip_bfloat16* eh     = (__hip_bfloat16*)(ws + O_EH);
  float*          gate   = (float*)(ws + O_GATE);
  float*          stats  = (float*)(ws + O_STATS);
  __hip_bfloat16* logits = (__hip_bfloat16*)(ws + O_LOG);

  const bool have_emb_ws = (ws_size >= WS_NEED);

  if (have_emb_ws) {
    __hip_bfloat16* embb = (__hip_bfloat16*)(ws + O_EMB);
    cvt_emb_kernel<<<2048, 256, 0, stream>>>(emb, embb);
    rmsnorm_gate_kernel<<<SEQ, 256, 0, stream>>>(x, nscale, gw, hbf, gate);
    gemm1_kernel<<<dim3(2, HDIM / 128, NEXP), 256, 0, stream>>>(hbf, ew, eh);
    // 10 M-tiles x 197 N-tiles (last N-tile covers the VP..50431 overhang,
    // stores guarded by v < VP)
    gemm2_8ph_kernel<<<10 * 197, 512, 0, stream>>>(eh, embb, logits);
  } else {
    rmsnorm_gate_kernel<<<SEQ, 256, 0, stream>>>(x, nscale, gw, hbf, gate);
    gemm1_kernel<<<dim3(2, HDIM / 128, NEXP), 256, 0, stream>>>(hbf, ew, eh);
    gemm2_kernel<<<dim3(M2 / 128, VP / 128), 256, 0, stream>>>(eh, emb, logits);
  }
  softmax_stats_kernel<<<M2, 256, 0, stream>>>(logits, gate, stats);
  mix_kernel<<<dim3((VOC + 255) / 256, SEQ), 256, 0, stream>>>(logits, stats, out);
}